// Round 17
// baseline (513.151 us; speedup 1.0000x reference)
//
#include <hip/hip_runtime.h>
#include <hip/hip_bf16.h>

typedef __attribute__((ext_vector_type(8))) short short8;
typedef __attribute__((ext_vector_type(4))) float f32x4;

typedef const void __attribute__((address_space(1)))* gptr_t;
typedef void __attribute__((address_space(3)))* sptr_t;

static __device__ __forceinline__ void gload_lds16(const void* g, void* l) {
  __builtin_amdgcn_global_load_lds((gptr_t)g, (sptr_t)l, 16, 0, 0);
}

static __device__ __forceinline__ unsigned short f2bf(float f) {
  unsigned int u = __float_as_uint(f);
  unsigned int r = (u + 0x7fffu + ((u >> 16) & 1u)) >> 16;
  return (unsigned short)r;
}
static __device__ __forceinline__ float bf2f(unsigned short b) {
  return __uint_as_float(((unsigned int)b) << 16);
}
// pack 2 f32 -> 2 bf16 in one u32 (v_cvt_pk_bf16_f32, RNE; lo=src0, hi=src1)
static __device__ __forceinline__ unsigned int cvt_pk_bf16(float lo, float hi) {
  unsigned int r;
  asm("v_cvt_pk_bf16_f32 %0, %1, %2" : "=v"(r) : "v"(lo), "v"(hi));
  return r;
}

// ---------------- fp32 -> bf16 (same layout) ----------------
__global__ void cvt_f32_to_bf16(const float* __restrict__ in,
                                unsigned short* __restrict__ out, int n) {
  int idx = blockIdx.x * blockDim.x + threadIdx.x;
  int stride = gridDim.x * blockDim.x;
  for (int i = idx * 4; i < n; i += stride * 4) {
    const float4 v = *reinterpret_cast<const float4*>(in + i);
    unsigned long long packed =
        (unsigned long long)f2bf(v.x) | ((unsigned long long)f2bf(v.y) << 16) |
        ((unsigned long long)f2bf(v.z) << 32) | ((unsigned long long)f2bf(v.w) << 48);
    *reinterpret_cast<unsigned long long*>(out + i) = packed;
  }
}

// ---------------- fp32 [K][N] -> bf16 [N][K] (convert + transpose) ----------------
__global__ void cvt_transpose_bf16(const float* __restrict__ in,
                                   unsigned short* __restrict__ out, int K, int N) {
  __shared__ unsigned short tile[32][33];
  int kt = blockIdx.y * 32, nt = blockIdx.x * 32;
  int tx = threadIdx.x & 31;
  int ty = threadIdx.x >> 5;  // 0..7
  #pragma unroll
  for (int i = 0; i < 32; i += 8)
    tile[ty + i][tx] = f2bf(in[(size_t)(kt + ty + i) * N + nt + tx]);
  __syncthreads();
  #pragma unroll
  for (int i = 0; i < 32; i += 8)
    out[(size_t)(nt + ty + i) * K + kt + tx] = tile[tx][ty + i];
}

// ---------------- V region of KV [4096][2048] -> VT [2][8][128][2048] ----------------
__global__ void transpose_v(const unsigned short* __restrict__ Vp,
                            unsigned short* __restrict__ VT, int vstride) {
  __shared__ unsigned short tile[32][33];
  int st = blockIdx.x * 32;
  int dt = blockIdx.y * 32;
  int bh = blockIdx.z;
  int b = bh >> 3, h = bh & 7;
  int tx = threadIdx.x & 31, ty = threadIdx.x >> 5;
  #pragma unroll
  for (int i = 0; i < 32; i += 8)
    tile[ty + i][tx] = Vp[(size_t)(b * 2048 + st + ty + i) * vstride + h * 128 + dt + tx];
  __syncthreads();
  #pragma unroll
  for (int i = 0; i < 32; i += 8)
    VT[(size_t)((b * 8 + h) * 128 + dt + ty + i) * 2048 + st + tx] = tile[tx][ty + i];
}

// ---------------- RoPE in place on bf16 [rows][rowstride], heads at col hh*128 ------
__global__ void rope_kernel(unsigned short* __restrict__ buf, int rows, int nheads,
                            int rowstride, float oscale) {
  int total = rows * nheads * 64;
  int idx = blockIdx.x * blockDim.x + threadIdx.x;
  if (idx >= total) return;
  int j = idx & 63;
  int hh = (idx >> 6) % nheads;
  int r = idx / (64 * nheads);
  int pos = r & 2047;
  float inv = expf(-(float)j * 0.14391157f);  // ln(10000)/64
  float ang = (float)pos * inv;
  float s, c;
  sincosf(ang, &s, &c);
  unsigned int* p =
      reinterpret_cast<unsigned int*>(buf + (size_t)r * rowstride + hh * 128 + 2 * j);
  unsigned int pv = *p;
  float x0 = bf2f((unsigned short)(pv & 0xffffu));
  float x1 = bf2f((unsigned short)(pv >> 16));
  float o0 = (x0 * c - x1 * s) * oscale;
  float o1 = (x0 * s + x1 * c) * oscale;
  *p = (unsigned int)f2bf(o0) | ((unsigned int)f2bf(o1) << 16);
}

static __device__ __forceinline__ void store_out(unsigned short* C, size_t idx, float v) {
  C[idx] = f2bf(v);
}
static __device__ __forceinline__ void store_out(float* C, size_t idx, float v) {
  C[idx] = v;
}

// ---------------- 256x256 8-phase GEMM (round-16 measured: 131.8us) ----------------
template <typename OutT>
__global__ __launch_bounds__(512) void gemm_8ph(const unsigned short* __restrict__ A,
                                                const unsigned short* __restrict__ BT,
                                                OutT* __restrict__ C, int M, int N,
                                                int K) {
  __shared__ __align__(16) unsigned short S[2][4][8192];
  const int tid = threadIdx.x;
  const int w = tid >> 6, lane = tid & 63;
  const int fr = lane & 15, fg = lane >> 4;
  const int wr = w >> 2, wc = w & 3;

  const int nbx = N >> 8;
  const int bid = blockIdx.x;
  const int cpx = gridDim.x >> 3;
  const int lid = (bid & 7) * cpx + (bid >> 3);
  const int brow = lid / nbx, bcol = lid % nbx;

  const int sr8 = lane >> 3;   // staging row-in-8
  const int sc8 = lane & 7;    // staging LDS chunk
  const int sgc = sc8 ^ sr8;   // pre-swizzled global source chunk
  const unsigned short* gA = A + (size_t)(brow * 256) * K;
  const unsigned short* gB = BT + (size_t)(bcol * 256) * K;
  const int NT = K >> 6;

  f32x4 acc[8][4] = {};

  auto stageHT = [&](int t, int ht) {
    if (t >= NT) t -= NT;
    const unsigned short* src = (ht < 2) ? gA : gB;
    const int half = ht & 1;
    unsigned short* dst = &S[t & 1][ht][0];
    #pragma unroll
    for (int l = 0; l < 2; l++) {
      const int rl = w * 16 + l * 8;
      gload_lds16(src + (size_t)(half * 128 + rl + sr8) * K + t * 64 + sgc * 8,
                  dst + rl * 64);
    }
  };

  stageHT(0, 0);
  stageHT(0, 1);
  stageHT(0, 2);
  stageHT(0, 3);
  stageHT(1, 2);
  stageHT(1, 3);
  asm volatile("s_waitcnt vmcnt(4)" ::: "memory");
  __builtin_amdgcn_s_barrier();

  const int rdswz = fr & 7;
  for (int t = 0; t < NT; t++) {
    const unsigned short* Sa = &S[t & 1][wr][0];
    const unsigned short* Sb = &S[t & 1][2 + (wc >> 1)][0];
    short8 bfr[4][2];
    #pragma unroll
    for (int q = 0; q < 4; q++) {
      short8 a[2][2];
      #pragma unroll
      for (int i = 0; i < 2; i++)
        #pragma unroll
        for (int ks = 0; ks < 2; ks++) {
          const int row = (2 * q + i) * 16 + fr;
          a[i][ks] = *reinterpret_cast<const short8*>(
              &Sa[row * 64 + ((ks * 4 + fg) ^ rdswz) * 8]);
        }
      if (q == 0) {
        #pragma unroll
        for (int n = 0; n < 4; n++)
          #pragma unroll
          for (int ks = 0; ks < 2; ks++) {
            const int row = (wc & 1) * 64 + n * 16 + fr;
            bfr[n][ks] = *reinterpret_cast<const short8*>(
                &Sb[row * 64 + ((ks * 4 + fg) ^ rdswz) * 8]);
          }
      }
      if (q < 2)
        stageHT(t + 1, q);
      else
        stageHT(t + 2, q);
      __builtin_amdgcn_s_barrier();
      asm volatile("s_waitcnt lgkmcnt(0)" ::: "memory");
      __builtin_amdgcn_sched_barrier(0);
      __builtin_amdgcn_s_setprio(1);
      #pragma unroll
      for (int i = 0; i < 2; i++)
        #pragma unroll
        for (int n = 0; n < 4; n++) {
          acc[2 * q + i][n] =
              __builtin_amdgcn_mfma_f32_16x16x32_bf16(a[i][0], bfr[n][0],
                                                      acc[2 * q + i][n], 0, 0, 0);
          acc[2 * q + i][n] =
              __builtin_amdgcn_mfma_f32_16x16x32_bf16(a[i][1], bfr[n][1],
                                                      acc[2 * q + i][n], 0, 0, 0);
        }
      __builtin_amdgcn_s_setprio(0);
      if (q == 3) asm volatile("s_waitcnt vmcnt(4)" ::: "memory");
      __builtin_amdgcn_s_barrier();
    }
  }
  asm volatile("s_waitcnt vmcnt(0)" ::: "memory");

  #pragma unroll
  for (int i = 0; i < 8; i++)
    #pragma unroll
    for (int n = 0; n < 4; n++)
      #pragma unroll
      for (int r = 0; r < 4; r++) {
        int row = brow * 256 + wr * 128 + i * 16 + fg * 4 + r;
        int col = bcol * 256 + wc * 64 + n * 16 + fr;
        store_out(C, (size_t)row * N + col, acc[i][n][r]);
      }
}

// ---------------- 128x256 merged-phase GEMM (verified; KV projection) ----------------
template <int AM, typename OutT>
__global__ __launch_bounds__(512) void gemm_bt256(const unsigned short* __restrict__ A,
                                                  const unsigned short* __restrict__ BT,
                                                  OutT* __restrict__ C, int M, int N,
                                                  int K) {
  constexpr int H = AM / 4;
  __shared__ __align__(16) unsigned short S[4][(AM + 16) * 512];
  const int tid = threadIdx.x;
  const int w = tid >> 6, lane = tid & 63;
  const int fr = lane & 15, fg = lane >> 4;
  const int wr = w >> 2, wc = w & 3;

  const int nbx = N >> 8;
  const int bid = blockIdx.x;
  const int cpx = gridDim.x >> 3;
  const int lid = (bid & 7) * cpx + (bid >> 3);
  const int brow = lid / nbx, bcol = lid % nbx;

  const int srl = lane >> 2;
  const int scc = (lane & 3) ^ (((lane >> 5) & 1) << 1);
  const unsigned short* gA = A + (size_t)(brow * (AM * 16)) * K;
  const unsigned short* gB = BT + (size_t)(bcol * 256) * K;

  f32x4 acc[2 * H][4] = {};
  const int rdoff = fr * 32 + ((fg ^ (((fr >> 3) & 1) << 1)) * 8);

  const int NT = K >> 5;

  for (int s = 0; s < 3; s++) {
    const int kb = s * 32;
    #pragma unroll
    for (int u = 0; u < AM / 8; u++) {
      int sb = (AM / 8) * w + u;
      gload_lds16(gA + (size_t)(sb * 16 + srl) * K + kb + scc * 8, &S[s][sb * 512]);
    }
    #pragma unroll
    for (int u = 0; u < 2; u++) {
      int sb = 2 * w + u;
      gload_lds16(gB + (size_t)(sb * 16 + srl) * K + kb + scc * 8,
                  &S[s][AM * 512 + sb * 512]);
    }
  }
  asm volatile("s_waitcnt vmcnt(6)" ::: "memory");
  __builtin_amdgcn_s_barrier();

  for (int s = 0; s < NT; s++) {
    const unsigned short* Sa = &S[s & 3][0];
    const unsigned short* Sb = &S[s & 3][AM * 512];
    const int bufn = (s + 3) & 3;
    int kn = s + 3;
    if (kn >= NT) kn -= NT;
    const int kbn = kn * 32;

    short8 b[4], a0[H], a1[H];
    #pragma unroll
    for (int j = 0; j < 4; j++)
      b[j] = *reinterpret_cast<const short8*>(&Sb[(wc * 4 + j) * 512 + rdoff]);
    #pragma unroll
    for (int i = 0; i < H; i++)
      a0[i] = *reinterpret_cast<const short8*>(&Sa[(wr * 2 * H + i) * 512 + rdoff]);
    #pragma unroll
    for (int i = 0; i < H; i++)
      a1[i] = *reinterpret_cast<const short8*>(&Sa[(wr * 2 * H + H + i) * 512 + rdoff]);
    #pragma unroll
    for (int u = 0; u < AM / 8; u++) {
      int sb = (AM / 8) * w + u;
      gload_lds16(gA + (size_t)(sb * 16 + srl) * K + kbn + scc * 8, &S[bufn][sb * 512]);
    }
    #pragma unroll
    for (int u = 0; u < 2; u++) {
      int sb = 2 * w + u;
      gload_lds16(gB + (size_t)(sb * 16 + srl) * K + kbn + scc * 8,
                  &S[bufn][AM * 512 + sb * 512]);
    }
    asm volatile("s_waitcnt lgkmcnt(2)" ::: "memory");
    __builtin_amdgcn_sched_barrier(0);
    __builtin_amdgcn_s_setprio(1);
    #pragma unroll
    for (int i = 0; i < H; i++)
      #pragma unroll
      for (int j = 0; j < 4; j++)
        acc[i][j] = __builtin_amdgcn_mfma_f32_16x16x32_bf16(a0[i], b[j], acc[i][j], 0, 0, 0);
    __builtin_amdgcn_s_setprio(0);
    __builtin_amdgcn_sched_barrier(0);
    asm volatile("s_waitcnt lgkmcnt(0)" ::: "memory");
    __builtin_amdgcn_sched_barrier(0);
    __builtin_amdgcn_s_setprio(1);
    #pragma unroll
    for (int i = 0; i < H; i++)
      #pragma unroll
      for (int j = 0; j < 4; j++)
        acc[H + i][j] =
            __builtin_amdgcn_mfma_f32_16x16x32_bf16(a1[i], b[j], acc[H + i][j], 0, 0, 0);
    __builtin_amdgcn_s_setprio(0);
    asm volatile("s_waitcnt vmcnt(6)" ::: "memory");
    __builtin_amdgcn_s_barrier();
  }

  #pragma unroll
  for (int i = 0; i < 2 * H; i++)
    #pragma unroll
    for (int j = 0; j < 4; j++)
      #pragma unroll
      for (int r = 0; r < 4; r++) {
        int row = brow * (AM * 16) + wr * (AM * 8) + i * 16 + fg * 4 + r;
        int col = bcol * 256 + wc * 64 + j * 16 + fr;
        store_out(C, (size_t)row * N + col, acc[i][j][r]);
      }
}

// ---------------- Flash attention (causal, GQA) — 8 waves x 16 q-rows ----------------
// Same tile/stage/sync skeleton as the verified 4-wave kernel (round-8/15: 133us),
// re-split: 512 threads, each wave owns 16 q-rows (the m=0 slice of the old code).
// 2x resident waves (16/CU) for latency hiding at the same 2-blocks/CU LDS budget.
// Staging per wave: 2 K + 2 V gloads -> counted vmcnt(4) (tail 0), same invariant.
// P_lds: [8][16][36] two-half flow (functionally verified in round 12).
// Q: [4096][4096] roped bf16 pre-scaled by log2(e)/sqrt(128)
// KV: [4096][2048] (K cols roped); VT: [2][8][128][2048]; O: [4096][4096] bf16
__global__ __launch_bounds__(512, 4) void flash_attn(const unsigned short* __restrict__ Q,
                                                     const unsigned short* __restrict__ KV,
                                                     const unsigned short* __restrict__ VT,
                                                     unsigned short* __restrict__ O) {
  __shared__ __align__(16) unsigned short K_lds[2][64][128];  // 32 KB
  __shared__ __align__(16) unsigned short V_lds[2][128][64];  // 32 KB
  __shared__ __align__(16) unsigned short P_lds[8][16][36];   // 9 KB, two-half reuse

  const int wave = threadIdx.x >> 6, lane = threadIdx.x & 63;
  const int fr = lane & 15, fg = lane >> 4;

  // XCD-bijective swizzle over 512 blocks
  const int bid = blockIdx.x;
  const int lid = (bid & 7) * 64 + (bid >> 3);
  const int pr = lid & 7;          // pair index 0..7 -> q-tiles {15-pr, pr}
  const int h = (lid >> 3) & 31;
  const int b = lid >> 8;
  const int kvh = h >> 2;

  const unsigned short* Qb = Q + (size_t)(b * 2048) * 4096 + h * 128;
  const unsigned short* Kb = KV + (size_t)(b * 2048) * 2048 + kvh * 128;
  const unsigned short* Vb = VT + (size_t)((b * 8 + kvh) * 128) * 2048;

  const int l4 = lane >> 4, c16 = lane & 15;  // K staging lanes: 4 rows x 16 chunks
  const int l3 = lane >> 3, c8 = lane & 7;    // V staging lanes: 8 rows x 8 chunks

  // per wave: rows [wave*8, wave*8+8) of K (2 gloads), [wave*16, wave*16+16) of V (2)
  auto stage = [&](int kb, int bf) {
    #pragma unroll
    for (int c = 0; c < 2; c++) {
      int rl = wave * 8 + c * 4 + l4;
      int ch = c16 ^ (rl & 7);
      gload_lds16(Kb + (size_t)(kb + rl) * 2048 + ch * 8, &K_lds[bf][wave * 8 + c * 4][0]);
    }
    #pragma unroll
    for (int c = 0; c < 2; c++) {
      int rl = wave * 16 + c * 8 + l3;
      int ch = c8 ^ (rl & 7);
      gload_lds16(Vb + (size_t)rl * 2048 + kb + ch * 8, &V_lds[bf][wave * 16 + c * 8][0]);
    }
  };

  for (int seg = 0; seg < 2; seg++) {
    const int blk = seg ? pr : 15 - pr;
    const int qw = blk * 128 + wave * 16;  // this wave's 16 q-rows

    // Q fragments: rows qw+fr, d = dk*32+fg*8
    short8 qf[4];
    #pragma unroll
    for (int dk = 0; dk < 4; dk++)
      qf[dk] = *reinterpret_cast<const short8*>(
          &Qb[(size_t)(qw + fr) * 4096 + dk * 32 + fg * 8]);

    float mrow = -INFINITY;
    float lrow = 0.f;
    f32x4 oacc[8] = {};

    const int nt = 2 * blk + 2;  // 64-key tiles this segment needs
    stage(0, 0);

    for (int t = 0; t < nt; t++) {
      const int kb = t * 64;
      if (t + 1 < nt) {
        stage((t + 1) * 64, (t + 1) & 1);
        asm volatile("s_waitcnt vmcnt(4)" ::: "memory");
      } else {
        asm volatile("s_waitcnt vmcnt(0)" ::: "memory");
      }
      __builtin_amdgcn_s_barrier();

      if (kb <= qw + 15) {
        const unsigned short* Kl = &K_lds[t & 1][0][0];
        const unsigned short* Vl = &V_lds[t & 1][0][0];

        // ---- QK^T: S^T[k_local = kc*16 + fg*4+r][q = fr] ----
        f32x4 s[4] = {};
        #pragma unroll
        for (int kc = 0; kc < 4; kc++) {
          short8 kf[4];
          #pragma unroll
          for (int dk = 0; dk < 4; dk++)
            kf[dk] = *reinterpret_cast<const short8*>(
                &Kl[(kc * 16 + fr) * 128 + (((dk * 4 + fg) ^ (fr & 7)) << 3)]);
          #pragma unroll
          for (int dk = 0; dk < 4; dk++)
            s[kc] = __builtin_amdgcn_mfma_f32_16x16x32_bf16(kf[dk], qf[dk], s[kc], 0, 0, 0);
        }
        if (kb + 63 > qw) {  // diagonal tile: causal mask (qi = qw + fr)
          const int qi = qw + fr;
          #pragma unroll
          for (int kc = 0; kc < 4; kc++)
            #pragma unroll
            for (int r = 0; r < 4; r++)
              if (kb + kc * 16 + fg * 4 + r > qi) s[kc][r] = -INFINITY;
        }

        // ---- online softmax (stats in q=fr domain) ----
        float mx = -INFINITY;
        #pragma unroll
        for (int kc = 0; kc < 4; kc++)
          #pragma unroll
          for (int r = 0; r < 4; r++) mx = fmaxf(mx, s[kc][r]);
        mx = fmaxf(mx, __shfl_xor(mx, 16));
        mx = fmaxf(mx, __shfl_xor(mx, 32));
        const bool need = !__all(mx - mrow <= 8.0f);  // defer-max (log2 domain)
        float mnew = need ? fmaxf(mrow, mx) : mrow;
        if (need) {
          float alpha = exp2f(mrow - mnew);
          lrow *= alpha;
          float alw[4];
          #pragma unroll
          for (int r = 0; r < 4; r++) alw[r] = __shfl(alpha, fg * 4 + r);
          #pragma unroll
          for (int dt = 0; dt < 8; dt++)
            #pragma unroll
            for (int r = 0; r < 4; r++) oacc[dt][r] *= alw[r];
        }
        float p_[16];
        float rs = 0.f;
        #pragma unroll
        for (int kc = 0; kc < 4; kc++)
          #pragma unroll
          for (int r = 0; r < 4; r++) {
            float pv = exp2f(s[kc][r] - mnew);
            p_[kc * 4 + r] = pv;
            rs += pv;
          }
        rs += __shfl_xor(rs, 16);
        rs += __shfl_xor(rs, 32);
        lrow += rs;
        mrow = mnew;

        // ---- P -> bf16 via per-wave LDS, two-half flow (DS in-order per wave) ----
        short8 pf[2];
        #pragma unroll
        for (int half = 0; half < 2; half++) {
          #pragma unroll
          for (int kc = 0; kc < 2; kc++) {
            int kk = half * 2 + kc;
            unsigned int lo = cvt_pk_bf16(p_[kk * 4 + 0], p_[kk * 4 + 1]);
            unsigned int hi = cvt_pk_bf16(p_[kk * 4 + 2], p_[kk * 4 + 3]);
            unsigned int* dst =
                reinterpret_cast<unsigned int*>(&P_lds[wave][fr][kc * 16 + fg * 4]);
            dst[0] = lo;
            dst[1] = hi;
          }
          pf[half] = *reinterpret_cast<const short8*>(&P_lds[wave][fr][fg * 8]);
        }

        // ---- PV: O[q = fg*4+r][d = dt*16+fr] ----
        #pragma unroll
        for (int c = 0; c < 2; c++)
          #pragma unroll
          for (int dt = 0; dt < 8; dt++) {
            short8 vf = *reinterpret_cast<const short8*>(
                &Vl[(dt * 16 + fr) * 64 + (((c * 4 + fg) ^ (fr & 7)) << 3)]);
            oacc[dt] = __builtin_amdgcn_mfma_f32_16x16x32_bf16(pf[c], vf, oacc[dt], 0, 0, 0);
          }
      }
      __builtin_amdgcn_s_barrier();
    }

    // ---- epilogue: redistribute 1/lrow (held at lane fr=q) to lanes q=fg*4+r ----
    float linv[4];
    #pragma unroll
    for (int r = 0; r < 4; r++) linv[r] = 1.0f / __shfl(lrow, fg * 4 + r);
    #pragma unroll
    for (int dt = 0; dt < 8; dt++)
      #pragma unroll
      for (int r = 0; r < 4; r++) {
        int row = qw + fg * 4 + r;
        float v = oacc[dt][r] * linv[r];
        O[(size_t)(b * 2048 + row) * 4096 + h * 128 + dt * 16 + fr] = f2bf(v);
      }
  }
}

// ---------------- launcher ----------------
extern "C" void kernel_launch(void* const* d_in, const int* in_sizes, int n_in,
                              void* d_out, int out_size, void* d_ws, size_t ws_size,
                              hipStream_t stream) {
  const float* x = (const float*)d_in[0];
  const float* Wq = (const float*)d_in[1];
  const float* Wk = (const float*)d_in[2];
  const float* Wv = (const float*)d_in[3];
  const float* Wo = (const float*)d_in[4];
  float* out = (float*)d_out;

  char* ws = (char*)d_ws;
  unsigned short* xb   = (unsigned short*)(ws + 0);          // 32 MB
  unsigned short* WqT  = (unsigned short*)(ws + 33554432);   // 32 MB
  unsigned short* WkvT = (unsigned short*)(ws + 67108864);   // 16 MB [2048][4096]
  unsigned short* WoT  = (unsigned short*)(ws + 83886080);   // 32 MB
  unsigned short* Qb   = (unsigned short*)(ws + 117440512);  // 32 MB
  unsigned short* KVb  = (unsigned short*)(ws + 150994944);  // 16 MB [4096][2048]
  unsigned short* VT   = (unsigned short*)(ws + 167772160);  // 8 MB
  unsigned short* Ob   = (unsigned short*)(ws + 176160768);  // 32 MB -> total 200 MB

  cvt_f32_to_bf16<<<2048, 256, 0, stream>>>(x, xb, 4096 * 4096);
  cvt_transpose_bf16<<<dim3(128, 128), 256, 0, stream>>>(Wq, WqT, 4096, 4096);
  cvt_transpose_bf16<<<dim3(32, 128), 256, 0, stream>>>(Wk, WkvT, 4096, 1024);
  cvt_transpose_bf16<<<dim3(32, 128), 256, 0, stream>>>(Wv, WkvT + (size_t)1024 * 4096,
                                                        4096, 1024);
  cvt_transpose_bf16<<<dim3(128, 128), 256, 0, stream>>>(Wo, WoT, 4096, 4096);

  gemm_8ph<unsigned short><<<256, 512, 0, stream>>>(xb, WqT, Qb, 4096, 4096, 4096);
  gemm_bt256<8, unsigned short><<<256, 512, 0, stream>>>(xb, WkvT, KVb, 4096, 2048, 4096);

  // Q pre-scaled by log2(e)/sqrt(HEAD_DIM) so flash softmax runs in exp2 domain
  rope_kernel<<<(4096 * 32 * 64 + 255) / 256, 256, 0, stream>>>(Qb, 4096, 32, 4096,
                                                                0.12751780f);
  rope_kernel<<<(4096 * 8 * 64 + 255) / 256, 256, 0, stream>>>(KVb, 4096, 8, 2048, 1.0f);

  transpose_v<<<dim3(64, 4, 16), 256, 0, stream>>>(KVb + 1024, VT, 2048);

  flash_attn<<<512, 512, 0, stream>>>(Qb, KVb, VT, Ob);

  gemm_8ph<float><<<256, 512, 0, stream>>>(Ob, WoT, out, 4096, 4096, 4096);
}

// Round 18
// 486.371 us; speedup vs baseline: 1.0551x; 1.0551x over previous
//
#include <hip/hip_runtime.h>
#include <hip/hip_bf16.h>

typedef __attribute__((ext_vector_type(8))) short short8;
typedef __attribute__((ext_vector_type(4))) float f32x4;

typedef const void __attribute__((address_space(1)))* gptr_t;
typedef void __attribute__((address_space(3)))* sptr_t;

static __device__ __forceinline__ void gload_lds16(const void* g, void* l) {
  __builtin_amdgcn_global_load_lds((gptr_t)g, (sptr_t)l, 16, 0, 0);
}

static __device__ __forceinline__ unsigned short f2bf(float f) {
  unsigned int u = __float_as_uint(f);
  unsigned int r = (u + 0x7fffu + ((u >> 16) & 1u)) >> 16;
  return (unsigned short)r;
}
static __device__ __forceinline__ float bf2f(unsigned short b) {
  return __uint_as_float(((unsigned int)b) << 16);
}
// pack 2 f32 -> 2 bf16 in one u32 (v_cvt_pk_bf16_f32, RNE; lo=src0, hi=src1)
static __device__ __forceinline__ unsigned int cvt_pk_bf16(float lo, float hi) {
  unsigned int r;
  asm("v_cvt_pk_bf16_f32 %0, %1, %2" : "=v"(r) : "v"(lo), "v"(hi));
  return r;
}

// ---------------- fp32 -> bf16 (same layout) ----------------
__global__ void cvt_f32_to_bf16(const float* __restrict__ in,
                                unsigned short* __restrict__ out, int n) {
  int idx = blockIdx.x * blockDim.x + threadIdx.x;
  int stride = gridDim.x * blockDim.x;
  for (int i = idx * 4; i < n; i += stride * 4) {
    const float4 v = *reinterpret_cast<const float4*>(in + i);
    unsigned long long packed =
        (unsigned long long)f2bf(v.x) | ((unsigned long long)f2bf(v.y) << 16) |
        ((unsigned long long)f2bf(v.z) << 32) | ((unsigned long long)f2bf(v.w) << 48);
    *reinterpret_cast<unsigned long long*>(out + i) = packed;
  }
}

// ---------------- fp32 [K][N] -> bf16 [N][K] (convert + transpose) ----------------
__global__ void cvt_transpose_bf16(const float* __restrict__ in,
                                   unsigned short* __restrict__ out, int K, int N) {
  __shared__ unsigned short tile[32][33];
  int kt = blockIdx.y * 32, nt = blockIdx.x * 32;
  int tx = threadIdx.x & 31;
  int ty = threadIdx.x >> 5;  // 0..7
  #pragma unroll
  for (int i = 0; i < 32; i += 8)
    tile[ty + i][tx] = f2bf(in[(size_t)(kt + ty + i) * N + nt + tx]);
  __syncthreads();
  #pragma unroll
  for (int i = 0; i < 32; i += 8)
    out[(size_t)(nt + ty + i) * K + kt + tx] = tile[tx][ty + i];
}

// ---------------- V region of KV [4096][2048] -> VT [2][8][128][2048] ----------------
__global__ void transpose_v(const unsigned short* __restrict__ Vp,
                            unsigned short* __restrict__ VT, int vstride) {
  __shared__ unsigned short tile[32][33];
  int st = blockIdx.x * 32;
  int dt = blockIdx.y * 32;
  int bh = blockIdx.z;
  int b = bh >> 3, h = bh & 7;
  int tx = threadIdx.x & 31, ty = threadIdx.x >> 5;
  #pragma unroll
  for (int i = 0; i < 32; i += 8)
    tile[ty + i][tx] = Vp[(size_t)(b * 2048 + st + ty + i) * vstride + h * 128 + dt + tx];
  __syncthreads();
  #pragma unroll
  for (int i = 0; i < 32; i += 8)
    VT[(size_t)((b * 8 + h) * 128 + dt + ty + i) * 2048 + st + tx] = tile[tx][ty + i];
}

static __device__ __forceinline__ void store_out(unsigned short* C, size_t idx, float v) {
  C[idx] = f2bf(v);
}
static __device__ __forceinline__ void store_out(float* C, size_t idx, float v) {
  C[idx] = v;
}

// Fused-RoPE epilogue helper: v at (row, col); partner value p from lane fr^1
// (cols pair-aligned). Rotates pairs (2j, 2j+1) with ang = (row mod 2048) * inv(j),
// scaled by oscale. Caller ensures both partner lanes execute the shfl.
static __device__ __forceinline__ float rope_elem(float v, float p, int row, int col,
                                                  int odd, float oscale) {
  const int j = (col & 127) >> 1;
  const float ang = (float)(row & 2047) * __expf(-(float)j * 0.14391157f);
  float sn, cs;
  __sincosf(ang, &sn, &cs);
  const float o = odd ? (p * sn + v * cs) : (v * cs - p * sn);
  return o * oscale;
}

// ---------------- 256x256 8-phase GEMM (round-16 measured: 131.8us) ----------------
// ROPE!=0: apply LLaMA RoPE (+oscale) to output cols < rlim in the epilogue.
template <int ROPE, typename OutT>
__global__ __launch_bounds__(512) void gemm_8ph(const unsigned short* __restrict__ A,
                                                const unsigned short* __restrict__ BT,
                                                OutT* __restrict__ C, int M, int N,
                                                int K, float oscale, int rlim) {
  __shared__ __align__(16) unsigned short S[2][4][8192];
  const int tid = threadIdx.x;
  const int w = tid >> 6, lane = tid & 63;
  const int fr = lane & 15, fg = lane >> 4;
  const int wr = w >> 2, wc = w & 3;

  const int nbx = N >> 8;
  const int bid = blockIdx.x;
  const int cpx = gridDim.x >> 3;
  const int lid = (bid & 7) * cpx + (bid >> 3);
  const int brow = lid / nbx, bcol = lid % nbx;

  const int sr8 = lane >> 3;   // staging row-in-8
  const int sc8 = lane & 7;    // staging LDS chunk
  const int sgc = sc8 ^ sr8;   // pre-swizzled global source chunk
  const unsigned short* gA = A + (size_t)(brow * 256) * K;
  const unsigned short* gB = BT + (size_t)(bcol * 256) * K;
  const int NT = K >> 6;

  f32x4 acc[8][4] = {};

  auto stageHT = [&](int t, int ht) {
    if (t >= NT) t -= NT;
    const unsigned short* src = (ht < 2) ? gA : gB;
    const int half = ht & 1;
    unsigned short* dst = &S[t & 1][ht][0];
    #pragma unroll
    for (int l = 0; l < 2; l++) {
      const int rl = w * 16 + l * 8;
      gload_lds16(src + (size_t)(half * 128 + rl + sr8) * K + t * 64 + sgc * 8,
                  dst + rl * 64);
    }
  };

  stageHT(0, 0);
  stageHT(0, 1);
  stageHT(0, 2);
  stageHT(0, 3);
  stageHT(1, 2);
  stageHT(1, 3);
  asm volatile("s_waitcnt vmcnt(4)" ::: "memory");
  __builtin_amdgcn_s_barrier();

  const int rdswz = fr & 7;
  for (int t = 0; t < NT; t++) {
    const unsigned short* Sa = &S[t & 1][wr][0];
    const unsigned short* Sb = &S[t & 1][2 + (wc >> 1)][0];
    short8 bfr[4][2];
    #pragma unroll
    for (int q = 0; q < 4; q++) {
      short8 a[2][2];
      #pragma unroll
      for (int i = 0; i < 2; i++)
        #pragma unroll
        for (int ks = 0; ks < 2; ks++) {
          const int row = (2 * q + i) * 16 + fr;
          a[i][ks] = *reinterpret_cast<const short8*>(
              &Sa[row * 64 + ((ks * 4 + fg) ^ rdswz) * 8]);
        }
      if (q == 0) {
        #pragma unroll
        for (int n = 0; n < 4; n++)
          #pragma unroll
          for (int ks = 0; ks < 2; ks++) {
            const int row = (wc & 1) * 64 + n * 16 + fr;
            bfr[n][ks] = *reinterpret_cast<const short8*>(
                &Sb[row * 64 + ((ks * 4 + fg) ^ rdswz) * 8]);
          }
      }
      if (q < 2)
        stageHT(t + 1, q);
      else
        stageHT(t + 2, q);
      __builtin_amdgcn_s_barrier();
      asm volatile("s_waitcnt lgkmcnt(0)" ::: "memory");
      __builtin_amdgcn_sched_barrier(0);
      __builtin_amdgcn_s_setprio(1);
      #pragma unroll
      for (int i = 0; i < 2; i++)
        #pragma unroll
        for (int n = 0; n < 4; n++) {
          acc[2 * q + i][n] =
              __builtin_amdgcn_mfma_f32_16x16x32_bf16(a[i][0], bfr[n][0],
                                                      acc[2 * q + i][n], 0, 0, 0);
          acc[2 * q + i][n] =
              __builtin_amdgcn_mfma_f32_16x16x32_bf16(a[i][1], bfr[n][1],
                                                      acc[2 * q + i][n], 0, 0, 0);
        }
      __builtin_amdgcn_s_setprio(0);
      if (q == 3) asm volatile("s_waitcnt vmcnt(4)" ::: "memory");
      __builtin_amdgcn_s_barrier();
    }
  }
  asm volatile("s_waitcnt vmcnt(0)" ::: "memory");

  #pragma unroll
  for (int i = 0; i < 8; i++)
    #pragma unroll
    for (int n = 0; n < 4; n++)
      #pragma unroll
      for (int r = 0; r < 4; r++) {
        int row = brow * 256 + wr * 128 + i * 16 + fg * 4 + r;
        int col = bcol * 256 + wc * 64 + n * 16 + fr;
        float v = acc[i][n][r];
        if constexpr (ROPE != 0) {
          float p = __shfl_xor(v, 1);  // partner col (pair-aligned)
          if (col < rlim) v = rope_elem(v, p, row, col, fr & 1, oscale);
        }
        store_out(C, (size_t)row * N + col, v);
      }
}

// ---------------- 128x256 merged-phase GEMM (verified; KV projection) ----------------
// ROPE!=0: apply RoPE to cols < rlim (K region) in the epilogue; V cols untouched.
template <int AM, int ROPE, typename OutT>
__global__ __launch_bounds__(512) void gemm_bt256(const unsigned short* __restrict__ A,
                                                  const unsigned short* __restrict__ BT,
                                                  OutT* __restrict__ C, int M, int N,
                                                  int K, float oscale, int rlim) {
  constexpr int H = AM / 4;
  __shared__ __align__(16) unsigned short S[4][(AM + 16) * 512];
  const int tid = threadIdx.x;
  const int w = tid >> 6, lane = tid & 63;
  const int fr = lane & 15, fg = lane >> 4;
  const int wr = w >> 2, wc = w & 3;

  const int nbx = N >> 8;
  const int bid = blockIdx.x;
  const int cpx = gridDim.x >> 3;
  const int lid = (bid & 7) * cpx + (bid >> 3);
  const int brow = lid / nbx, bcol = lid % nbx;

  const int srl = lane >> 2;
  const int scc = (lane & 3) ^ (((lane >> 5) & 1) << 1);
  const unsigned short* gA = A + (size_t)(brow * (AM * 16)) * K;
  const unsigned short* gB = BT + (size_t)(bcol * 256) * K;

  f32x4 acc[2 * H][4] = {};
  const int rdoff = fr * 32 + ((fg ^ (((fr >> 3) & 1) << 1)) * 8);

  const int NT = K >> 5;

  for (int s = 0; s < 3; s++) {
    const int kb = s * 32;
    #pragma unroll
    for (int u = 0; u < AM / 8; u++) {
      int sb = (AM / 8) * w + u;
      gload_lds16(gA + (size_t)(sb * 16 + srl) * K + kb + scc * 8, &S[s][sb * 512]);
    }
    #pragma unroll
    for (int u = 0; u < 2; u++) {
      int sb = 2 * w + u;
      gload_lds16(gB + (size_t)(sb * 16 + srl) * K + kb + scc * 8,
                  &S[s][AM * 512 + sb * 512]);
    }
  }
  asm volatile("s_waitcnt vmcnt(6)" ::: "memory");
  __builtin_amdgcn_s_barrier();

  for (int s = 0; s < NT; s++) {
    const unsigned short* Sa = &S[s & 3][0];
    const unsigned short* Sb = &S[s & 3][AM * 512];
    const int bufn = (s + 3) & 3;
    int kn = s + 3;
    if (kn >= NT) kn -= NT;
    const int kbn = kn * 32;

    short8 b[4], a0[H], a1[H];
    #pragma unroll
    for (int j = 0; j < 4; j++)
      b[j] = *reinterpret_cast<const short8*>(&Sb[(wc * 4 + j) * 512 + rdoff]);
    #pragma unroll
    for (int i = 0; i < H; i++)
      a0[i] = *reinterpret_cast<const short8*>(&Sa[(wr * 2 * H + i) * 512 + rdoff]);
    #pragma unroll
    for (int i = 0; i < H; i++)
      a1[i] = *reinterpret_cast<const short8*>(&Sa[(wr * 2 * H + H + i) * 512 + rdoff]);
    #pragma unroll
    for (int u = 0; u < AM / 8; u++) {
      int sb = (AM / 8) * w + u;
      gload_lds16(gA + (size_t)(sb * 16 + srl) * K + kbn + scc * 8, &S[bufn][sb * 512]);
    }
    #pragma unroll
    for (int u = 0; u < 2; u++) {
      int sb = 2 * w + u;
      gload_lds16(gB + (size_t)(sb * 16 + srl) * K + kbn + scc * 8,
                  &S[bufn][AM * 512 + sb * 512]);
    }
    asm volatile("s_waitcnt lgkmcnt(2)" ::: "memory");
    __builtin_amdgcn_sched_barrier(0);
    __builtin_amdgcn_s_setprio(1);
    #pragma unroll
    for (int i = 0; i < H; i++)
      #pragma unroll
      for (int j = 0; j < 4; j++)
        acc[i][j] = __builtin_amdgcn_mfma_f32_16x16x32_bf16(a0[i], b[j], acc[i][j], 0, 0, 0);
    __builtin_amdgcn_s_setprio(0);
    __builtin_amdgcn_sched_barrier(0);
    asm volatile("s_waitcnt lgkmcnt(0)" ::: "memory");
    __builtin_amdgcn_sched_barrier(0);
    __builtin_amdgcn_s_setprio(1);
    #pragma unroll
    for (int i = 0; i < H; i++)
      #pragma unroll
      for (int j = 0; j < 4; j++)
        acc[H + i][j] =
            __builtin_amdgcn_mfma_f32_16x16x32_bf16(a1[i], b[j], acc[H + i][j], 0, 0, 0);
    __builtin_amdgcn_s_setprio(0);
    asm volatile("s_waitcnt vmcnt(6)" ::: "memory");
    __builtin_amdgcn_s_barrier();
  }

  #pragma unroll
  for (int i = 0; i < 2 * H; i++)
    #pragma unroll
    for (int j = 0; j < 4; j++)
      #pragma unroll
      for (int r = 0; r < 4; r++) {
        int row = brow * (AM * 16) + wr * (AM * 8) + i * 16 + fg * 4 + r;
        int col = bcol * 256 + wc * 64 + j * 16 + fr;
        float v = acc[i][j][r];
        if constexpr (ROPE != 0) {
          float p = __shfl_xor(v, 1);  // partner col (pair-aligned; rlim even)
          if (col < rlim) v = rope_elem(v, p, row, col, fr & 1, oscale);
        }
        store_out(C, (size_t)row * N + col, v);
      }
}

// ---------------- Flash attention (causal, GQA) — 8 waves x 16 q-rows ----------------
// [round-17 verified: <131 us] Same tile/stage/sync skeleton as the 4-wave kernel.
// Q: [4096][4096] roped bf16 pre-scaled by log2(e)/sqrt(128)
// KV: [4096][2048] (K cols roped); VT: [2][8][128][2048]; O: [4096][4096] bf16
__global__ __launch_bounds__(512, 4) void flash_attn(const unsigned short* __restrict__ Q,
                                                     const unsigned short* __restrict__ KV,
                                                     const unsigned short* __restrict__ VT,
                                                     unsigned short* __restrict__ O) {
  __shared__ __align__(16) unsigned short K_lds[2][64][128];  // 32 KB
  __shared__ __align__(16) unsigned short V_lds[2][128][64];  // 32 KB
  __shared__ __align__(16) unsigned short P_lds[8][16][36];   // 9 KB, two-half reuse

  const int wave = threadIdx.x >> 6, lane = threadIdx.x & 63;
  const int fr = lane & 15, fg = lane >> 4;

  const int bid = blockIdx.x;
  const int lid = (bid & 7) * 64 + (bid >> 3);
  const int pr = lid & 7;          // pair index 0..7 -> q-tiles {15-pr, pr}
  const int h = (lid >> 3) & 31;
  const int b = lid >> 8;
  const int kvh = h >> 2;

  const unsigned short* Qb = Q + (size_t)(b * 2048) * 4096 + h * 128;
  const unsigned short* Kb = KV + (size_t)(b * 2048) * 2048 + kvh * 128;
  const unsigned short* Vb = VT + (size_t)((b * 8 + kvh) * 128) * 2048;

  const int l4 = lane >> 4, c16 = lane & 15;  // K staging lanes: 4 rows x 16 chunks
  const int l3 = lane >> 3, c8 = lane & 7;    // V staging lanes: 8 rows x 8 chunks

  auto stage = [&](int kb, int bf) {
    #pragma unroll
    for (int c = 0; c < 2; c++) {
      int rl = wave * 8 + c * 4 + l4;
      int ch = c16 ^ (rl & 7);
      gload_lds16(Kb + (size_t)(kb + rl) * 2048 + ch * 8, &K_lds[bf][wave * 8 + c * 4][0]);
    }
    #pragma unroll
    for (int c = 0; c < 2; c++) {
      int rl = wave * 16 + c * 8 + l3;
      int ch = c8 ^ (rl & 7);
      gload_lds16(Vb + (size_t)rl * 2048 + kb + ch * 8, &V_lds[bf][wave * 16 + c * 8][0]);
    }
  };

  for (int seg = 0; seg < 2; seg++) {
    const int blk = seg ? pr : 15 - pr;
    const int qw = blk * 128 + wave * 16;  // this wave's 16 q-rows

    short8 qf[4];
    #pragma unroll
    for (int dk = 0; dk < 4; dk++)
      qf[dk] = *reinterpret_cast<const short8*>(
          &Qb[(size_t)(qw + fr) * 4096 + dk * 32 + fg * 8]);

    float mrow = -INFINITY;
    float lrow = 0.f;
    f32x4 oacc[8] = {};

    const int nt = 2 * blk + 2;  // 64-key tiles this segment needs
    stage(0, 0);

    for (int t = 0; t < nt; t++) {
      const int kb = t * 64;
      if (t + 1 < nt) {
        stage((t + 1) * 64, (t + 1) & 1);
        asm volatile("s_waitcnt vmcnt(4)" ::: "memory");
      } else {
        asm volatile("s_waitcnt vmcnt(0)" ::: "memory");
      }
      __builtin_amdgcn_s_barrier();

      if (kb <= qw + 15) {
        const unsigned short* Kl = &K_lds[t & 1][0][0];
        const unsigned short* Vl = &V_lds[t & 1][0][0];

        f32x4 s[4] = {};
        #pragma unroll
        for (int kc = 0; kc < 4; kc++) {
          short8 kf[4];
          #pragma unroll
          for (int dk = 0; dk < 4; dk++)
            kf[dk] = *reinterpret_cast<const short8*>(
                &Kl[(kc * 16 + fr) * 128 + (((dk * 4 + fg) ^ (fr & 7)) << 3)]);
          #pragma unroll
          for (int dk = 0; dk < 4; dk++)
            s[kc] = __builtin_amdgcn_mfma_f32_16x16x32_bf16(kf[dk], qf[dk], s[kc], 0, 0, 0);
        }
        if (kb + 63 > qw) {
          const int qi = qw + fr;
          #pragma unroll
          for (int kc = 0; kc < 4; kc++)
            #pragma unroll
            for (int r = 0; r < 4; r++)
              if (kb + kc * 16 + fg * 4 + r > qi) s[kc][r] = -INFINITY;
        }

        float mx = -INFINITY;
        #pragma unroll
        for (int kc = 0; kc < 4; kc++)
          #pragma unroll
          for (int r = 0; r < 4; r++) mx = fmaxf(mx, s[kc][r]);
        mx = fmaxf(mx, __shfl_xor(mx, 16));
        mx = fmaxf(mx, __shfl_xor(mx, 32));
        const bool need = !__all(mx - mrow <= 8.0f);
        float mnew = need ? fmaxf(mrow, mx) : mrow;
        if (need) {
          float alpha = exp2f(mrow - mnew);
          lrow *= alpha;
          float alw[4];
          #pragma unroll
          for (int r = 0; r < 4; r++) alw[r] = __shfl(alpha, fg * 4 + r);
          #pragma unroll
          for (int dt = 0; dt < 8; dt++)
            #pragma unroll
            for (int r = 0; r < 4; r++) oacc[dt][r] *= alw[r];
        }
        float p_[16];
        float rs = 0.f;
        #pragma unroll
        for (int kc = 0; kc < 4; kc++)
          #pragma unroll
          for (int r = 0; r < 4; r++) {
            float pv = exp2f(s[kc][r] - mnew);
            p_[kc * 4 + r] = pv;
            rs += pv;
          }
        rs += __shfl_xor(rs, 16);
        rs += __shfl_xor(rs, 32);
        lrow += rs;
        mrow = mnew;

        short8 pf[2];
        #pragma unroll
        for (int half = 0; half < 2; half++) {
          #pragma unroll
          for (int kc = 0; kc < 2; kc++) {
            int kk = half * 2 + kc;
            unsigned int lo = cvt_pk_bf16(p_[kk * 4 + 0], p_[kk * 4 + 1]);
            unsigned int hi = cvt_pk_bf16(p_[kk * 4 + 2], p_[kk * 4 + 3]);
            unsigned int* dst =
                reinterpret_cast<unsigned int*>(&P_lds[wave][fr][kc * 16 + fg * 4]);
            dst[0] = lo;
            dst[1] = hi;
          }
          pf[half] = *reinterpret_cast<const short8*>(&P_lds[wave][fr][fg * 8]);
        }

        #pragma unroll
        for (int c = 0; c < 2; c++)
          #pragma unroll
          for (int dt = 0; dt < 8; dt++) {
            short8 vf = *reinterpret_cast<const short8*>(
                &Vl[(dt * 16 + fr) * 64 + (((c * 4 + fg) ^ (fr & 7)) << 3)]);
            oacc[dt] = __builtin_amdgcn_mfma_f32_16x16x32_bf16(pf[c], vf, oacc[dt], 0, 0, 0);
          }
      }
      __builtin_amdgcn_s_barrier();
    }

    float linv[4];
    #pragma unroll
    for (int r = 0; r < 4; r++) linv[r] = 1.0f / __shfl(lrow, fg * 4 + r);
    #pragma unroll
    for (int dt = 0; dt < 8; dt++)
      #pragma unroll
      for (int r = 0; r < 4; r++) {
        int row = qw + fg * 4 + r;
        float v = oacc[dt][r] * linv[r];
        O[(size_t)(b * 2048 + row) * 4096 + h * 128 + dt * 16 + fr] = f2bf(v);
      }
  }
}

// ---------------- launcher ----------------
extern "C" void kernel_launch(void* const* d_in, const int* in_sizes, int n_in,
                              void* d_out, int out_size, void* d_ws, size_t ws_size,
                              hipStream_t stream) {
  const float* x = (const float*)d_in[0];
  const float* Wq = (const float*)d_in[1];
  const float* Wk = (const float*)d_in[2];
  const float* Wv = (const float*)d_in[3];
  const float* Wo = (const float*)d_in[4];
  float* out = (float*)d_out;

  char* ws = (char*)d_ws;
  unsigned short* xb   = (unsigned short*)(ws + 0);          // 32 MB
  unsigned short* WqT  = (unsigned short*)(ws + 33554432);   // 32 MB
  unsigned short* WkvT = (unsigned short*)(ws + 67108864);   // 16 MB [2048][4096]
  unsigned short* WoT  = (unsigned short*)(ws + 83886080);   // 32 MB
  unsigned short* Qb   = (unsigned short*)(ws + 117440512);  // 32 MB
  unsigned short* KVb  = (unsigned short*)(ws + 150994944);  // 16 MB [4096][2048]
  unsigned short* VT   = (unsigned short*)(ws + 167772160);  // 8 MB
  unsigned short* Ob   = (unsigned short*)(ws + 176160768);  // 32 MB -> total 200 MB

  cvt_f32_to_bf16<<<2048, 256, 0, stream>>>(x, xb, 4096 * 4096);
  cvt_transpose_bf16<<<dim3(128, 128), 256, 0, stream>>>(Wq, WqT, 4096, 4096);
  cvt_transpose_bf16<<<dim3(32, 128), 256, 0, stream>>>(Wk, WkvT, 4096, 1024);
  cvt_transpose_bf16<<<dim3(32, 128), 256, 0, stream>>>(Wv, WkvT + (size_t)1024 * 4096,
                                                        4096, 1024);
  cvt_transpose_bf16<<<dim3(128, 128), 256, 0, stream>>>(Wo, WoT, 4096, 4096);

  // Q projection with fused RoPE + log2(e)/sqrt(128) scale (exp2-domain softmax)
  gemm_8ph<1, unsigned short><<<256, 512, 0, stream>>>(xb, WqT, Qb, 4096, 4096, 4096,
                                                       0.12751780f, 4096);
  // KV projection: RoPE on K columns (col < 1024) only, unit scale
  gemm_bt256<8, 1, unsigned short><<<256, 512, 0, stream>>>(xb, WkvT, KVb, 4096, 2048,
                                                            4096, 1.0f, 1024);

  transpose_v<<<dim3(64, 4, 16), 256, 0, stream>>>(KVb + 1024, VT, 2048);

  flash_attn<<<512, 512, 0, stream>>>(Qb, KVb, VT, Ob);

  gemm_8ph<0, float><<<256, 512, 0, stream>>>(Ob, WoT, out, 4096, 4096, 4096, 1.0f, 0);
}